// Round 1
// baseline (854.319 us; speedup 1.0000x reference)
//
#include <hip/hip_runtime.h>

// GCN 2-layer forward on MI355X:
//   H  = Y @ W1                (50000x256 · 256x256, fp32 vector GEMM)
//   HA = relu(spmm(A, H))      (CSR gather per row, 256 feats)
//   G  = HA @ W2               (50000x256 · 256x128)
//   out= spmm(A, G)            (128 feats)
// CSR built on-device every call (histogram -> scan -> scatter), so the
// float aggregation needs no atomics.

#define NN 50000

// ---------------- CSR build ----------------

__global__ void hist_kernel(const int* __restrict__ erow, int* __restrict__ cnt, int E) {
    int i = blockIdx.x * blockDim.x + threadIdx.x;
    int stride = gridDim.x * blockDim.x;
    for (; i < E; i += stride) atomicAdd(&cnt[erow[i]], 1);
}

__global__ __launch_bounds__(1024) void scan_kernel(const int* __restrict__ cnt,
                                                    int* __restrict__ row_ptr,
                                                    int* __restrict__ cursor, int n) {
    __shared__ int lds[1024];
    int t = threadIdx.x;
    int chunk = (n + 1023) >> 10;
    int lo = t * chunk;
    int hi = min(n, lo + chunk);
    int s = 0;
    for (int i = lo; i < hi; ++i) s += cnt[i];
    lds[t] = s;
    __syncthreads();
    // Hillis-Steele inclusive scan over 1024 partials
    for (int off = 1; off < 1024; off <<= 1) {
        int v = (t >= off) ? lds[t - off] : 0;
        __syncthreads();
        lds[t] += v;
        __syncthreads();
    }
    int run = lds[t] - s;  // exclusive prefix
    for (int i = lo; i < hi; ++i) {
        row_ptr[i] = run;
        cursor[i] = run;
        run += cnt[i];
    }
    if (t == 1023) row_ptr[n] = run;  // t=1023's chunk is empty -> run == E
}

__global__ void scatter_kernel(const int* __restrict__ erow, int* __restrict__ cursor,
                               int* __restrict__ eperm, int E) {
    int i = blockIdx.x * blockDim.x + threadIdx.x;
    int stride = gridDim.x * blockDim.x;
    for (; i < E; i += stride) {
        int r = erow[i];
        int pos = atomicAdd(&cursor[r], 1);
        eperm[pos] = i;
    }
}

// ---------------- fp32 SGEMM: C[MxN] = A[MxK] @ B[KxN] ----------------
// 128x128 tile, BK=8, 256 threads, 8x8 per-thread microtile.
__global__ __launch_bounds__(256) void gemm_f32(const float* __restrict__ A,
                                                const float* __restrict__ B,
                                                float* __restrict__ C,
                                                int M, int N, int K) {
    __shared__ float As[8][128];
    __shared__ float Bs[8][128];
    const int tid = threadIdx.x;
    const int m0 = blockIdx.x * 128;
    const int n0 = blockIdx.y * 128;
    const int tx = tid & 15;   // n-direction, 16 threads
    const int ty = tid >> 4;   // m-direction, 16 threads

    float acc[8][8];
#pragma unroll
    for (int i = 0; i < 8; ++i)
#pragma unroll
        for (int j = 0; j < 8; ++j) acc[i][j] = 0.f;

    const int li = tid * 4;
    const int am = li >> 3;    // A tile row (0..127)
    const int ak = li & 7;     // A tile col (0 or 4)
    const int bk = li >> 7;    // B tile row (0..7)
    const int bn = li & 127;   // B tile col (multiple of 4)

    for (int k0 = 0; k0 < K; k0 += 8) {
        // A tile: 128 rows x 8 cols, 4 elems/thread (same row)
        float4 av = make_float4(0.f, 0.f, 0.f, 0.f);
        int grow = m0 + am;
        if (grow < M)
            av = *reinterpret_cast<const float4*>(&A[(size_t)grow * K + k0 + ak]);
        As[ak + 0][am] = av.x;
        As[ak + 1][am] = av.y;
        As[ak + 2][am] = av.z;
        As[ak + 3][am] = av.w;
        // B tile: 8 rows x 128 cols (N is a multiple of 128, K of 8: no guards)
        float4 bv = *reinterpret_cast<const float4*>(&B[(size_t)(k0 + bk) * N + n0 + bn]);
        *reinterpret_cast<float4*>(&Bs[bk][bn]) = bv;
        __syncthreads();

#pragma unroll
        for (int kk = 0; kk < 8; ++kk) {
            float a[8], b[8];
#pragma unroll
            for (int i = 0; i < 8; ++i) a[i] = As[kk][ty * 8 + i];
#pragma unroll
            for (int j = 0; j < 8; ++j) b[j] = Bs[kk][tx * 8 + j];
#pragma unroll
            for (int i = 0; i < 8; ++i)
#pragma unroll
                for (int j = 0; j < 8; ++j) acc[i][j] = fmaf(a[i], b[j], acc[i][j]);
        }
        __syncthreads();
    }

#pragma unroll
    for (int i = 0; i < 8; ++i) {
        int grow = m0 + ty * 8 + i;
        if (grow < M) {
            float* crow = &C[(size_t)grow * N + n0 + tx * 8];
            *reinterpret_cast<float4*>(crow) =
                make_float4(acc[i][0], acc[i][1], acc[i][2], acc[i][3]);
            *reinterpret_cast<float4*>(crow + 4) =
                make_float4(acc[i][4], acc[i][5], acc[i][6], acc[i][7]);
        }
    }
}

// ---------------- CSR SpMM: Y[r] = sum_{e in row r} val[e] * X[col[e]] ----------------
// One block per row, one thread per feature. D = 256 (w/ relu) or 128.
template <int D, bool RELU>
__global__ __launch_bounds__(256) void spmm_kernel(const int* __restrict__ row_ptr,
                                                   const int* __restrict__ eperm,
                                                   const int* __restrict__ ecol,
                                                   const float* __restrict__ eval_,
                                                   const float* __restrict__ X,
                                                   float* __restrict__ Y) {
    const int r = blockIdx.x;
    const int f = threadIdx.x;
    const int s = row_ptr[r];
    const int e = row_ptr[r + 1];
    float acc = 0.f;
    for (int i = s; i < e; ++i) {
        int ed = eperm[i];
        float v = eval_[ed];
        int c = ecol[ed];
        acc += v * X[(size_t)c * D + f];
    }
    Y[(size_t)r * D + f] = RELU ? fmaxf(acc, 0.f) : acc;
}

// ---------------- launch ----------------

extern "C" void kernel_launch(void* const* d_in, const int* in_sizes, int n_in,
                              void* d_out, int out_size, void* d_ws, size_t ws_size,
                              hipStream_t stream) {
    const float* Y     = (const float*)d_in[0];
    const int*   erow  = (const int*)d_in[1];
    const int*   ecol  = (const int*)d_in[2];
    const float* eval_ = (const float*)d_in[3];
    const float* W1    = (const float*)d_in[4];
    const float* W2    = (const float*)d_in[5];
    float* out = (float*)d_out;
    const int E = in_sizes[1];
    const int N = NN;

    // Workspace layout (bytes):
    //   H  : N*256*4 = 51.2 MB   (also aliased as G = N*128*4 later)
    //   HA : N*256*4 = 51.2 MB
    //   row_ptr (N+1), cursor (N), cnt (N), eperm (E) ints (~3.8 MB)
    char* ws = (char*)d_ws;
    float* H  = (float*)ws;
    float* HA = (float*)(ws + (size_t)N * 256 * 4);
    char* ib = ws + (size_t)N * 256 * 4 * 2;
    int* row_ptr = (int*)ib;
    int* cursor  = (int*)(ib + (size_t)(N + 1) * 4);
    int* cnt     = (int*)(ib + (size_t)(N + 1) * 4 + (size_t)N * 4);
    int* eperm   = (int*)(ib + (size_t)(N + 1) * 4 + (size_t)N * 4 * 2);
    float* G = H;  // H is dead once HA is computed

    // CSR build
    hipMemsetAsync(cnt, 0, (size_t)N * 4, stream);
    hist_kernel<<<512, 256, 0, stream>>>(erow, cnt, E);
    scan_kernel<<<1, 1024, 0, stream>>>(cnt, row_ptr, cursor, N);
    scatter_kernel<<<512, 256, 0, stream>>>(erow, cursor, eperm, E);

    // Layer 1
    gemm_f32<<<dim3((N + 127) / 128, 2), 256, 0, stream>>>(Y, W1, H, N, 256, 256);
    spmm_kernel<256, true><<<N, 256, 0, stream>>>(row_ptr, eperm, ecol, eval_, H, HA);

    // Layer 2
    gemm_f32<<<dim3((N + 127) / 128, 1), 256, 0, stream>>>(HA, W2, G, N, 128, 256);
    spmm_kernel<128, false><<<N, 128, 0, stream>>>(row_ptr, eperm, ecol, eval_, G, out);
}

// Round 3
// 627.135 us; speedup vs baseline: 1.3623x; 1.3623x over previous
//
#include <hip/hip_runtime.h>

// GCN 2-layer forward on MI355X:
//   H  = Y @ W1                (50000x256 · 256x256, fp32 vector GEMM)
//   HA = relu(spmm(A, H))      (CSR gather per row, 256 feats)
//   G  = HA @ W2               (50000x256 · 256x128)
//   out= spmm(A, G)            (128 feats)
// CSR built on-device every call (histogram -> scan -> scatter (col,val) pairs),
// so the float aggregation needs no atomics and SpMM has no eperm indirection.
// SpMM: one WAVE per row, float4/float2 per lane, 4x unrolled gathers for
// memory-level parallelism (R1 showed latency-bound: VALUBusy 4.4%, 1.9 TB/s).

#define NN 50000

// ---------------- CSR build ----------------

__global__ void hist_kernel(const int* __restrict__ erow, int* __restrict__ cnt, int E) {
    int i = blockIdx.x * blockDim.x + threadIdx.x;
    int stride = gridDim.x * blockDim.x;
    for (; i < E; i += stride) atomicAdd(&cnt[erow[i]], 1);
}

__global__ __launch_bounds__(1024) void scan_kernel(const int* __restrict__ cnt,
                                                    int* __restrict__ row_ptr,
                                                    int* __restrict__ cursor, int n) {
    __shared__ int lds[1024];
    int t = threadIdx.x;
    int chunk = (n + 1023) >> 10;
    int lo = t * chunk;
    int hi = min(n, lo + chunk);
    int s = 0;
    for (int i = lo; i < hi; ++i) s += cnt[i];
    lds[t] = s;
    __syncthreads();
    // Hillis-Steele inclusive scan over 1024 partials
    for (int off = 1; off < 1024; off <<= 1) {
        int v = (t >= off) ? lds[t - off] : 0;
        __syncthreads();
        lds[t] += v;
        __syncthreads();
    }
    int run = lds[t] - s;  // exclusive prefix
    for (int i = lo; i < hi; ++i) {
        row_ptr[i] = run;
        cursor[i] = run;
        run += cnt[i];
    }
    if (t == 1023) row_ptr[n] = run;  // t=1023's chunk is empty -> run == E
}

// Scatter (col, val) pairs directly into CSR order: SpMM then reads meta[]
// contiguously (wave-uniform, HW-broadcast) with no second indirection.
__global__ void scatter_kernel(const int* __restrict__ erow, const int* __restrict__ ecol,
                               const float* __restrict__ eval_, int* __restrict__ cursor,
                               int2* __restrict__ meta, int E) {
    int i = blockIdx.x * blockDim.x + threadIdx.x;
    int stride = gridDim.x * blockDim.x;
    for (; i < E; i += stride) {
        int r = erow[i];
        int pos = atomicAdd(&cursor[r], 1);
        meta[pos] = make_int2(ecol[i], __float_as_int(eval_[i]));
    }
}

// ---------------- fp32 SGEMM: C[MxN] = A[MxK] @ B[KxN] ----------------
// 128x128 tile, BK=8, 256 threads, 8x8 per-thread microtile.
__global__ __launch_bounds__(256) void gemm_f32(const float* __restrict__ A,
                                                const float* __restrict__ B,
                                                float* __restrict__ C,
                                                int M, int N, int K) {
    __shared__ float As[8][128];
    __shared__ float Bs[8][128];
    const int tid = threadIdx.x;
    const int m0 = blockIdx.x * 128;
    const int n0 = blockIdx.y * 128;
    const int tx = tid & 15;   // n-direction
    const int ty = tid >> 4;   // m-direction

    float acc[8][8];
#pragma unroll
    for (int i = 0; i < 8; ++i)
#pragma unroll
        for (int j = 0; j < 8; ++j) acc[i][j] = 0.f;

    const int li = tid * 4;
    const int am = li >> 3;
    const int ak = li & 7;
    const int bk = li >> 7;
    const int bn = li & 127;

    for (int k0 = 0; k0 < K; k0 += 8) {
        float4 av = make_float4(0.f, 0.f, 0.f, 0.f);
        int grow = m0 + am;
        if (grow < M)
            av = *reinterpret_cast<const float4*>(&A[(size_t)grow * K + k0 + ak]);
        As[ak + 0][am] = av.x;
        As[ak + 1][am] = av.y;
        As[ak + 2][am] = av.z;
        As[ak + 3][am] = av.w;
        float4 bv = *reinterpret_cast<const float4*>(&B[(size_t)(k0 + bk) * N + n0 + bn]);
        *reinterpret_cast<float4*>(&Bs[bk][bn]) = bv;
        __syncthreads();

#pragma unroll
        for (int kk = 0; kk < 8; ++kk) {
            float a[8], b[8];
#pragma unroll
            for (int i = 0; i < 8; ++i) a[i] = As[kk][ty * 8 + i];
#pragma unroll
            for (int j = 0; j < 8; ++j) b[j] = Bs[kk][tx * 8 + j];
#pragma unroll
            for (int i = 0; i < 8; ++i)
#pragma unroll
                for (int j = 0; j < 8; ++j) acc[i][j] = fmaf(a[i], b[j], acc[i][j]);
        }
        __syncthreads();
    }

#pragma unroll
    for (int i = 0; i < 8; ++i) {
        int grow = m0 + ty * 8 + i;
        if (grow < M) {
            float* crow = &C[(size_t)grow * N + n0 + tx * 8];
            *reinterpret_cast<float4*>(crow) =
                make_float4(acc[i][0], acc[i][1], acc[i][2], acc[i][3]);
            *reinterpret_cast<float4*>(crow + 4) =
                make_float4(acc[i][4], acc[i][5], acc[i][6], acc[i][7]);
        }
    }
}

// ---------------- CSR SpMM: Y[r] = sum_{e in row r} val[e] * X[col[e]] ----------------
// One WAVE per row; lane holds VEC=D/64 contiguous features (float4 / float2).
// 4x unrolled edge loop -> 4 gathers in flight per wave (up to 4 KB outstanding).

template <int VEC>
__device__ inline void gather_row(const float* __restrict__ p, float (&x)[VEC]) {
    if constexpr (VEC == 4) {
        float4 t = *reinterpret_cast<const float4*>(p);
        x[0] = t.x; x[1] = t.y; x[2] = t.z; x[3] = t.w;
    } else {
        float2 t = *reinterpret_cast<const float2*>(p);
        x[0] = t.x; x[1] = t.y;
    }
}

template <int D, bool RELU>
__global__ __launch_bounds__(256) void spmm_kernel(const int* __restrict__ row_ptr,
                                                   const int2* __restrict__ meta,
                                                   const float* __restrict__ X,
                                                   float* __restrict__ Y, int nrows) {
    constexpr int VEC = D / 64;
    const int lane = threadIdx.x & 63;
    const int r = blockIdx.x * 4 + (threadIdx.x >> 6);
    if (r >= nrows) return;
    const int s = row_ptr[r];
    const int e = row_ptr[r + 1];
    const float* __restrict__ base = X + (size_t)lane * VEC;

    float acc[VEC];
#pragma unroll
    for (int k = 0; k < VEC; ++k) acc[k] = 0.f;

    int i = s;
    for (; i + 4 <= e; i += 4) {
        int2 m0 = meta[i], m1 = meta[i + 1], m2 = meta[i + 2], m3 = meta[i + 3];
        float x0[VEC], x1[VEC], x2[VEC], x3[VEC];
        gather_row<VEC>(base + (size_t)m0.x * D, x0);
        gather_row<VEC>(base + (size_t)m1.x * D, x1);
        gather_row<VEC>(base + (size_t)m2.x * D, x2);
        gather_row<VEC>(base + (size_t)m3.x * D, x3);
        float v0 = __int_as_float(m0.y), v1 = __int_as_float(m1.y);
        float v2 = __int_as_float(m2.y), v3 = __int_as_float(m3.y);
#pragma unroll
        for (int k = 0; k < VEC; ++k) acc[k] = fmaf(v0, x0[k], acc[k]);
#pragma unroll
        for (int k = 0; k < VEC; ++k) acc[k] = fmaf(v1, x1[k], acc[k]);
#pragma unroll
        for (int k = 0; k < VEC; ++k) acc[k] = fmaf(v2, x2[k], acc[k]);
#pragma unroll
        for (int k = 0; k < VEC; ++k) acc[k] = fmaf(v3, x3[k], acc[k]);
    }
    for (; i < e; ++i) {
        int2 m = meta[i];
        float x[VEC];
        gather_row<VEC>(base + (size_t)m.x * D, x);
        float v = __int_as_float(m.y);
#pragma unroll
        for (int k = 0; k < VEC; ++k) acc[k] = fmaf(v, x[k], acc[k]);
    }

    float* yp = Y + (size_t)r * D + lane * VEC;
    if constexpr (VEC == 4) {
        float4 t;
        t.x = RELU ? fmaxf(acc[0], 0.f) : acc[0];
        t.y = RELU ? fmaxf(acc[1], 0.f) : acc[1];
        t.z = RELU ? fmaxf(acc[2], 0.f) : acc[2];
        t.w = RELU ? fmaxf(acc[3], 0.f) : acc[3];
        *reinterpret_cast<float4*>(yp) = t;
    } else {
        float2 t;
        t.x = RELU ? fmaxf(acc[0], 0.f) : acc[0];
        t.y = RELU ? fmaxf(acc[1], 0.f) : acc[1];
        *reinterpret_cast<float2*>(yp) = t;
    }
}

// ---------------- launch ----------------

extern "C" void kernel_launch(void* const* d_in, const int* in_sizes, int n_in,
                              void* d_out, int out_size, void* d_ws, size_t ws_size,
                              hipStream_t stream) {
    const float* Y     = (const float*)d_in[0];
    const int*   erow  = (const int*)d_in[1];
    const int*   ecol  = (const int*)d_in[2];
    const float* eval_ = (const float*)d_in[3];
    const float* W1    = (const float*)d_in[4];
    const float* W2    = (const float*)d_in[5];
    float* out = (float*)d_out;
    const int E = in_sizes[1];
    const int N = NN;

    // Workspace layout:
    //   H  : N*256*4 = 51.2 MB   (aliased as G = N*128*4 later)
    //   HA : N*256*4 = 51.2 MB
    //   row_ptr (N+1), cursor (N), cnt (N) ints; meta (E int2) = 6.4 MB
    char* ws = (char*)d_ws;
    float* H  = (float*)ws;
    float* HA = (float*)(ws + (size_t)N * 256 * 4);
    char* ib = ws + (size_t)N * 256 * 4 * 2;
    int* row_ptr = (int*)ib;
    int* cursor  = (int*)(ib + (size_t)(N + 1) * 4);
    int* cnt     = (int*)(ib + (size_t)(N + 1) * 4 + (size_t)N * 4);
    int2* meta   = (int2*)(ib + (size_t)(N + 1) * 4 + (size_t)N * 4 * 2);
    float* G = H;  // H is dead once HA is computed

    // CSR build
    hipMemsetAsync(cnt, 0, (size_t)N * 4, stream);
    hist_kernel<<<512, 256, 0, stream>>>(erow, cnt, E);
    scan_kernel<<<1, 1024, 0, stream>>>(cnt, row_ptr, cursor, N);
    scatter_kernel<<<512, 256, 0, stream>>>(erow, ecol, eval_, cursor, meta, E);

    // Layer 1
    gemm_f32<<<dim3((N + 127) / 128, 2), 256, 0, stream>>>(Y, W1, H, N, 256, 256);
    spmm_kernel<256, true><<<(N + 3) / 4, 256, 0, stream>>>(row_ptr, meta, H, HA, N);

    // Layer 2
    gemm_f32<<<dim3((N + 127) / 128, 1), 256, 0, stream>>>(HA, W2, G, N, 128, 256);
    spmm_kernel<128, false><<<(N + 3) / 4, 256, 0, stream>>>(row_ptr, meta, G, out, N);
}

// Round 4
// 617.447 us; speedup vs baseline: 1.3836x; 1.0157x over previous
//
#include <hip/hip_runtime.h>

// GCN 2-layer forward on MI355X (R4):
//   split Y -> Yh,Yl (bf16 hi/lo)               ~20 us
//   H  = Y @ W1   via 3-pass bf16 MFMA          (error ~2^-17, ~fp32)
//   HA = relu(spmm(A, H)) -> HAh,HAl (split in epilogue, free)
//   G  = HA @ W2  via 3-pass bf16 MFMA
//   out= spmm(A, G)
// SpMM: wave per row, 8x unrolled float4/float2 gathers (R3: 4x unroll gave
// 2.4x; VALUBusy 11% => still latency headroom).
// GEMM: no-LDS; 4 waves/block; A/B frags are contiguous 16B loads from
// pre-split bf16 arrays (W pre-transposed to [n][k]).

#define NN 50000

typedef short s8v __attribute__((ext_vector_type(8)));  // 8 bf16 in 4 VGPRs
typedef float f4v __attribute__((ext_vector_type(4)));

// ---------------- bf16 hi/lo split helpers ----------------

__device__ inline unsigned int bf16_rne_bits(float x) {
    unsigned int u = __float_as_uint(x);
    return (u + 0x7FFFu + ((u >> 16) & 1u)) >> 16;  // round-to-nearest-even
}
__device__ inline float bf16_bits_to_f32(unsigned int h) {
    return __uint_as_float(h << 16);
}
__device__ inline void split_hi_lo(float x, unsigned short& hi, unsigned short& lo) {
    unsigned int h = bf16_rne_bits(x);
    hi = (unsigned short)h;
    lo = (unsigned short)bf16_rne_bits(x - bf16_bits_to_f32(h));
}

// ---------------- CSR build ----------------

__global__ void hist_kernel(const int* __restrict__ erow, int* __restrict__ cnt, int E) {
    int i = blockIdx.x * blockDim.x + threadIdx.x;
    int stride = gridDim.x * blockDim.x;
    for (; i < E; i += stride) atomicAdd(&cnt[erow[i]], 1);
}

__global__ __launch_bounds__(1024) void scan_kernel(const int* __restrict__ cnt,
                                                    int* __restrict__ row_ptr,
                                                    int* __restrict__ cursor, int n) {
    __shared__ int lds[1024];
    int t = threadIdx.x;
    int chunk = (n + 1023) >> 10;
    int lo = t * chunk;
    int hi = min(n, lo + chunk);
    int s = 0;
    for (int i = lo; i < hi; ++i) s += cnt[i];
    lds[t] = s;
    __syncthreads();
    for (int off = 1; off < 1024; off <<= 1) {
        int v = (t >= off) ? lds[t - off] : 0;
        __syncthreads();
        lds[t] += v;
        __syncthreads();
    }
    int run = lds[t] - s;  // exclusive prefix
    for (int i = lo; i < hi; ++i) {
        row_ptr[i] = run;
        cursor[i] = run;
        run += cnt[i];
    }
    if (t == 1023) row_ptr[n] = run;  // t=1023's chunk is empty -> run == E
}

__global__ void scatter_kernel(const int* __restrict__ erow, const int* __restrict__ ecol,
                               const float* __restrict__ eval_, int* __restrict__ cursor,
                               int2* __restrict__ meta, int E) {
    int i = blockIdx.x * blockDim.x + threadIdx.x;
    int stride = gridDim.x * blockDim.x;
    for (; i < E; i += stride) {
        int r = erow[i];
        int pos = atomicAdd(&cursor[r], 1);
        meta[pos] = make_int2(ecol[i], __float_as_int(eval_[i]));
    }
}

// ---------------- split / transpose-split passes ----------------

__global__ __launch_bounds__(256) void split_kernel(const float* __restrict__ X,
                                                    unsigned short* __restrict__ Xh,
                                                    unsigned short* __restrict__ Xl, int n4) {
    int i = blockIdx.x * blockDim.x + threadIdx.x;
    int stride = gridDim.x * blockDim.x;
    for (; i < n4; i += stride) {
        float4 v = reinterpret_cast<const float4*>(X)[i];
        ushort4 h, l;
        split_hi_lo(v.x, h.x, l.x);
        split_hi_lo(v.y, h.y, l.y);
        split_hi_lo(v.z, h.z, l.z);
        split_hi_lo(v.w, h.w, l.w);
        reinterpret_cast<ushort4*>(Xh)[i] = h;
        reinterpret_cast<ushort4*>(Xl)[i] = l;
    }
}

// W [K][N] fp32  ->  Wt hi/lo [N][K] bf16
__global__ __launch_bounds__(256) void wsplit_kernel(const float* __restrict__ W,
                                                     unsigned short* __restrict__ Wth,
                                                     unsigned short* __restrict__ Wtl,
                                                     int K, int N) {
    int idx = blockIdx.x * blockDim.x + threadIdx.x;
    if (idx >= K * N) return;
    int k = idx / N, n = idx - k * N;
    unsigned short h, l;
    split_hi_lo(W[idx], h, l);
    Wth[(size_t)n * K + k] = h;
    Wtl[(size_t)n * K + k] = l;
}

// ---------------- 3-pass bf16 MFMA GEMM ----------------
// C[M][N] = A[M][256] * B[256][N], A pre-split (Ah,Al row-major), B pre-split
// + transposed (Bth,Btl as [N][256]). Block: 256 thr = 4 waves; block owns 32
// rows; wave owns NF*16 cols. Frag layout (m89/m91-verified):
//   A: row = lane&15, k = 8*(lane>>4)+i  (contiguous 8 bf16 -> b128 load)
//   B: col = lane&15, k = 8*(lane>>4)+i
//   D: col = lane&15, row = 4*(lane>>4)+i
template <int NF>
__global__ __launch_bounds__(256) void gemm3p(const unsigned short* __restrict__ Ah,
                                              const unsigned short* __restrict__ Al,
                                              const unsigned short* __restrict__ Bth,
                                              const unsigned short* __restrict__ Btl,
                                              float* __restrict__ C, int M) {
    constexpr int K = 256;
    constexpr int N = NF * 64;  // 4 waves * NF frags * 16
    const int tid = threadIdx.x;
    const int wave = tid >> 6;
    const int l = tid & 63;
    const int r = l & 15;
    const int b = l >> 4;
    const int m0 = blockIdx.x * 32;
    const int n0 = wave * (NF * 16);

    const unsigned short* ap[2][2];
#pragma unroll
    for (int mf = 0; mf < 2; ++mf) {
        int row = min(m0 + mf * 16 + r, M - 1);  // clamped dup-read; store guarded
        ap[mf][0] = Ah + (size_t)row * K + b * 8;
        ap[mf][1] = Al + (size_t)row * K + b * 8;
    }
    const unsigned short* bp[NF][2];
#pragma unroll
    for (int nf = 0; nf < NF; ++nf) {
        int row = n0 + nf * 16 + r;
        bp[nf][0] = Bth + (size_t)row * K + b * 8;
        bp[nf][1] = Btl + (size_t)row * K + b * 8;
    }

    f4v acc[2][NF];
#pragma unroll
    for (int mf = 0; mf < 2; ++mf)
#pragma unroll
        for (int nf = 0; nf < NF; ++nf) acc[mf][nf] = (f4v){0.f, 0.f, 0.f, 0.f};

    for (int ks = 0; ks < K / 32; ++ks) {
        s8v ah[2], al[2];
#pragma unroll
        for (int mf = 0; mf < 2; ++mf) {
            ah[mf] = *reinterpret_cast<const s8v*>(ap[mf][0] + ks * 32);
            al[mf] = *reinterpret_cast<const s8v*>(ap[mf][1] + ks * 32);
        }
#pragma unroll
        for (int nf = 0; nf < NF; ++nf) {
            s8v bh = *reinterpret_cast<const s8v*>(bp[nf][0] + ks * 32);
            s8v bl = *reinterpret_cast<const s8v*>(bp[nf][1] + ks * 32);
#pragma unroll
            for (int mf = 0; mf < 2; ++mf) {
                acc[mf][nf] = __builtin_amdgcn_mfma_f32_16x16x32_bf16(ah[mf], bh, acc[mf][nf], 0, 0, 0);
                acc[mf][nf] = __builtin_amdgcn_mfma_f32_16x16x32_bf16(ah[mf], bl, acc[mf][nf], 0, 0, 0);
                acc[mf][nf] = __builtin_amdgcn_mfma_f32_16x16x32_bf16(al[mf], bh, acc[mf][nf], 0, 0, 0);
            }
        }
    }

#pragma unroll
    for (int mf = 0; mf < 2; ++mf)
#pragma unroll
        for (int i = 0; i < 4; ++i) {
            int row = m0 + mf * 16 + b * 4 + i;
            if (row < M) {
#pragma unroll
                for (int nf = 0; nf < NF; ++nf)
                    C[(size_t)row * N + n0 + nf * 16 + r] = acc[mf][nf][i];
            }
        }
}

// ---------------- CSR SpMM ----------------
// Wave per row; lane holds VEC=D/64 feats; 8x unrolled gathers.
// SPLITOUT: relu then write bf16 hi/lo (feeds gemm2). Else fp32 out.

template <int VEC>
__device__ inline void gather_row(const float* __restrict__ p, float (&x)[VEC]) {
    if constexpr (VEC == 4) {
        float4 t = *reinterpret_cast<const float4*>(p);
        x[0] = t.x; x[1] = t.y; x[2] = t.z; x[3] = t.w;
    } else {
        float2 t = *reinterpret_cast<const float2*>(p);
        x[0] = t.x; x[1] = t.y;
    }
}

template <int D, bool SPLITOUT>
__global__ __launch_bounds__(256) void spmm_kernel(const int* __restrict__ row_ptr,
                                                   const int2* __restrict__ meta,
                                                   const float* __restrict__ X,
                                                   float* __restrict__ Yo,
                                                   unsigned short* __restrict__ Yh,
                                                   unsigned short* __restrict__ Yl,
                                                   int nrows) {
    constexpr int VEC = D / 64;
    const int lane = threadIdx.x & 63;
    const int r = blockIdx.x * 4 + (threadIdx.x >> 6);
    if (r >= nrows) return;
    const int s = row_ptr[r];
    const int e = row_ptr[r + 1];
    const float* __restrict__ base = X + (size_t)lane * VEC;

    float acc[VEC];
#pragma unroll
    for (int k = 0; k < VEC; ++k) acc[k] = 0.f;

    int i = s;
    for (; i + 8 <= e; i += 8) {
        int2 mm[8];
        float xv[8][VEC];
#pragma unroll
        for (int u = 0; u < 8; ++u) mm[u] = meta[i + u];
#pragma unroll
        for (int u = 0; u < 8; ++u) gather_row<VEC>(base + (size_t)mm[u].x * D, xv[u]);
#pragma unroll
        for (int u = 0; u < 8; ++u) {
            float v = __int_as_float(mm[u].y);
#pragma unroll
            for (int k = 0; k < VEC; ++k) acc[k] = fmaf(v, xv[u][k], acc[k]);
        }
    }
    for (; i + 4 <= e; i += 4) {
        int2 mm[4];
        float xv[4][VEC];
#pragma unroll
        for (int u = 0; u < 4; ++u) mm[u] = meta[i + u];
#pragma unroll
        for (int u = 0; u < 4; ++u) gather_row<VEC>(base + (size_t)mm[u].x * D, xv[u]);
#pragma unroll
        for (int u = 0; u < 4; ++u) {
            float v = __int_as_float(mm[u].y);
#pragma unroll
            for (int k = 0; k < VEC; ++k) acc[k] = fmaf(v, xv[u][k], acc[k]);
        }
    }
    for (; i < e; ++i) {
        int2 m = meta[i];
        float x[VEC];
        gather_row<VEC>(base + (size_t)m.x * D, x);
        float v = __int_as_float(m.y);
#pragma unroll
        for (int k = 0; k < VEC; ++k) acc[k] = fmaf(v, x[k], acc[k]);
    }

    if constexpr (SPLITOUT) {
        static_assert(VEC == 4, "split path assumes D=256");
        ushort4 h, l;
        float a0 = fmaxf(acc[0], 0.f), a1 = fmaxf(acc[1], 0.f);
        float a2 = fmaxf(acc[2], 0.f), a3 = fmaxf(acc[3], 0.f);
        split_hi_lo(a0, h.x, l.x);
        split_hi_lo(a1, h.y, l.y);
        split_hi_lo(a2, h.z, l.z);
        split_hi_lo(a3, h.w, l.w);
        reinterpret_cast<ushort4*>(Yh + (size_t)r * D)[lane] = h;
        reinterpret_cast<ushort4*>(Yl + (size_t)r * D)[lane] = l;
    } else {
        float* yp = Yo + (size_t)r * D + lane * VEC;
        if constexpr (VEC == 4) {
            *reinterpret_cast<float4*>(yp) = make_float4(acc[0], acc[1], acc[2], acc[3]);
        } else {
            *reinterpret_cast<float2*>(yp) = make_float2(acc[0], acc[1]);
        }
    }
}

// ---------------- launch ----------------

extern "C" void kernel_launch(void* const* d_in, const int* in_sizes, int n_in,
                              void* d_out, int out_size, void* d_ws, size_t ws_size,
                              hipStream_t stream) {
    const float* Y     = (const float*)d_in[0];
    const int*   erow  = (const int*)d_in[1];
    const int*   ecol  = (const int*)d_in[2];
    const float* eval_ = (const float*)d_in[3];
    const float* W1    = (const float*)d_in[4];
    const float* W2    = (const float*)d_in[5];
    float* out = (float*)d_out;
    const int E = in_sizes[1];
    const int N = NN;

    // Workspace (~110 MB):
    //   [0, 25.6M)        Yh   (later HAh)
    //   [25.6M, 51.2M)    Yl   (later HAl)
    //   [51.2M, 102.4M)   H fp32 (later G fp32, 25.6M used)
    //   then W splits, row_ptr/cursor/cnt, meta
    char* ws = (char*)d_ws;
    unsigned short* Yh = (unsigned short*)ws;
    unsigned short* Yl = (unsigned short*)(ws + 25600000);
    float* H = (float*)(ws + 51200000);
    char* p = ws + 102400000;
    unsigned short* W1th = (unsigned short*)p; p += 131072;
    unsigned short* W1tl = (unsigned short*)p; p += 131072;
    unsigned short* W2th = (unsigned short*)p; p += 65536;
    unsigned short* W2tl = (unsigned short*)p; p += 65536;
    int* row_ptr = (int*)p; p += 200016;           // (N+1)*4 padded
    int* cursor  = (int*)p; p += 200000;
    int* cnt     = (int*)p; p += 200000;
    int2* meta   = (int2*)p;                       // E*8 = 6.4 MB

    // CSR build
    hipMemsetAsync(cnt, 0, (size_t)N * 4, stream);
    hist_kernel<<<512, 256, 0, stream>>>(erow, cnt, E);
    scan_kernel<<<1, 1024, 0, stream>>>(cnt, row_ptr, cursor, N);
    scatter_kernel<<<512, 256, 0, stream>>>(erow, ecol, eval_, cursor, meta, E);

    // Input splits
    split_kernel<<<2048, 256, 0, stream>>>(Y, Yh, Yl, N * 256 / 4);
    wsplit_kernel<<<256, 256, 0, stream>>>(W1, W1th, W1tl, 256, 256);
    wsplit_kernel<<<128, 256, 0, stream>>>(W2, W2th, W2tl, 256, 128);

    // Layer 1
    gemm3p<4><<<(N + 31) / 32, 256, 0, stream>>>(Yh, Yl, W1th, W1tl, H, N);
    spmm_kernel<256, true><<<(N + 3) / 4, 256, 0, stream>>>(row_ptr, meta, H, nullptr, Yh, Yl, N);

    // Layer 2 (HAh/HAl alias Yh/Yl; G aliases H)
    gemm3p<2><<<(N + 31) / 32, 256, 0, stream>>>(Yh, Yl, W2th, W2tl, H, N);
    spmm_kernel<128, false><<<(N + 3) / 4, 256, 0, stream>>>(row_ptr, meta, H, out, nullptr, nullptr, N);
}

// Round 5
// 438.230 us; speedup vs baseline: 1.9495x; 1.4090x over previous
//
#include <hip/hip_runtime.h>

// GCN 2-layer forward on MI355X (R5):
//   split Y -> Yh,Yl bf16 hi/lo
//   Hb  = bf16( Y @ W1 )     3-product bf16 MFMA GEMM, bf16 output
//   HA  = relu(spmm(A, Hb))  bf16 gathers, fp32 accum -> HAh/HAl hi/lo split
//   Gb  = bf16( HA @ W2 )    3-product MFMA, bf16 output
//   out = spmm(A, Gb)        bf16 gathers, fp32 accum, fp32 out
// R4 counters: spmm256 pinned at 3.75 TB/s moving 436 MB (byte-bound theory)
// -> bf16 gather operand halves bytes. Edge meta scalarized via readfirstlane.
// 1-block scan replaced with 3-kernel parallel scan.

#define NN 50000

typedef short s8v __attribute__((ext_vector_type(8)));  // 8 bf16 in 4 VGPRs
typedef float f4v __attribute__((ext_vector_type(4)));

// ---------------- bf16 helpers ----------------

__device__ inline unsigned int bf16_rne_bits(float x) {
    unsigned int u = __float_as_uint(x);
    return (u + 0x7FFFu + ((u >> 16) & 1u)) >> 16;  // round-to-nearest-even
}
__device__ inline float bf16_bits_to_f32(unsigned int h) {
    return __uint_as_float(h << 16);
}
__device__ inline void split_hi_lo(float x, unsigned short& hi, unsigned short& lo) {
    unsigned int h = bf16_rne_bits(x);
    hi = (unsigned short)h;
    lo = (unsigned short)bf16_rne_bits(x - bf16_bits_to_f32(h));
}
// unpack a uint holding 2 bf16 (little-endian) into 2 floats
__device__ inline void unpack2(unsigned int u, float& f0, float& f1) {
    f0 = __uint_as_float(u << 16);
    f1 = __uint_as_float(u & 0xFFFF0000u);
}

// ---------------- CSR build ----------------

__global__ void hist_kernel(const int* __restrict__ erow, int* __restrict__ cnt, int E) {
    int i = blockIdx.x * blockDim.x + threadIdx.x;
    int stride = gridDim.x * blockDim.x;
    for (; i < E; i += stride) atomicAdd(&cnt[erow[i]], 1);
}

// 3-phase parallel exclusive scan of cnt[n] -> row_ptr, cursor.
// 256 blocks x chunk of 196 elements (256*196 = 50176 >= 50000).
#define SCAN_CHUNK 196

__global__ __launch_bounds__(256) void scan_local(const int* __restrict__ cnt,
                                                  int* __restrict__ row_ptr,
                                                  int* __restrict__ partial, int n) {
    __shared__ int lds[256];
    int t = threadIdx.x, b = blockIdx.x;
    int idx = b * SCAN_CHUNK + t;
    int v = (t < SCAN_CHUNK && idx < n) ? cnt[idx] : 0;
    lds[t] = v;
    __syncthreads();
#pragma unroll
    for (int off = 1; off < 256; off <<= 1) {
        int a = (t >= off) ? lds[t - off] : 0;
        __syncthreads();
        lds[t] += a;
        __syncthreads();
    }
    if (t < SCAN_CHUNK && idx < n) row_ptr[idx] = lds[t] - v;  // local exclusive
    if (t == 255) partial[b] = lds[255];
}

__global__ __launch_bounds__(256) void scan_tot(int* __restrict__ partial) {
    __shared__ int lds[256];
    int t = threadIdx.x;
    int v = partial[t];
    lds[t] = v;
    __syncthreads();
#pragma unroll
    for (int off = 1; off < 256; off <<= 1) {
        int a = (t >= off) ? lds[t - off] : 0;
        __syncthreads();
        lds[t] += a;
        __syncthreads();
    }
    partial[t] = lds[t] - v;  // exclusive block offset
}

__global__ __launch_bounds__(256) void scan_add(int* __restrict__ row_ptr,
                                                int* __restrict__ cursor,
                                                const int* __restrict__ partial,
                                                int n, int E) {
    int t = threadIdx.x, b = blockIdx.x;
    int idx = b * SCAN_CHUNK + t;
    if (t < SCAN_CHUNK && idx < n) {
        int rp = row_ptr[idx] + partial[b];
        row_ptr[idx] = rp;
        cursor[idx] = rp;
    }
    if (b == 0 && t == 0) row_ptr[n] = E;
}

__global__ void scatter_kernel(const int* __restrict__ erow, const int* __restrict__ ecol,
                               const float* __restrict__ eval_, int* __restrict__ cursor,
                               int2* __restrict__ meta, int E) {
    int i = blockIdx.x * blockDim.x + threadIdx.x;
    int stride = gridDim.x * blockDim.x;
    for (; i < E; i += stride) {
        int r = erow[i];
        int pos = atomicAdd(&cursor[r], 1);
        meta[pos] = make_int2(ecol[i], __float_as_int(eval_[i]));
    }
}

// ---------------- split / transpose-split passes ----------------

__global__ __launch_bounds__(256) void split_kernel(const float* __restrict__ X,
                                                    unsigned short* __restrict__ Xh,
                                                    unsigned short* __restrict__ Xl, int n4) {
    int i = blockIdx.x * blockDim.x + threadIdx.x;
    int stride = gridDim.x * blockDim.x;
    for (; i < n4; i += stride) {
        float4 v = reinterpret_cast<const float4*>(X)[i];
        ushort4 h, l;
        split_hi_lo(v.x, h.x, l.x);
        split_hi_lo(v.y, h.y, l.y);
        split_hi_lo(v.z, h.z, l.z);
        split_hi_lo(v.w, h.w, l.w);
        reinterpret_cast<ushort4*>(Xh)[i] = h;
        reinterpret_cast<ushort4*>(Xl)[i] = l;
    }
}

// W [K][N] fp32  ->  Wt hi/lo [N][K] bf16
__global__ __launch_bounds__(256) void wsplit_kernel(const float* __restrict__ W,
                                                     unsigned short* __restrict__ Wth,
                                                     unsigned short* __restrict__ Wtl,
                                                     int K, int N) {
    int idx = blockIdx.x * blockDim.x + threadIdx.x;
    if (idx >= K * N) return;
    int k = idx / N, n = idx - k * N;
    unsigned short h, l;
    split_hi_lo(W[idx], h, l);
    Wth[(size_t)n * K + k] = h;
    Wtl[(size_t)n * K + k] = l;
}

// ---------------- 3-pass bf16 MFMA GEMM, bf16 output ----------------
// C[M][N] bf16 = A[M][256] * B[256][N]; A pre-split (Ah,Al row-major bf16),
// B pre-split + transposed (Bth,Btl as [N][256] bf16).
// Block: 256 thr = 4 waves; block owns 32 rows; wave owns NF*16 cols.
// Frag layout (m89/m91-verified):
//   A: row = lane&15, k = 8*(lane>>4)+i   B: col = lane&15, same k
//   D: col = lane&15, row = 4*(lane>>4)+i
template <int NF>
__global__ __launch_bounds__(256) void gemm3p(const unsigned short* __restrict__ Ah,
                                              const unsigned short* __restrict__ Al,
                                              const unsigned short* __restrict__ Bth,
                                              const unsigned short* __restrict__ Btl,
                                              unsigned short* __restrict__ C, int M) {
    constexpr int K = 256;
    constexpr int N = NF * 64;
    const int tid = threadIdx.x;
    const int wave = tid >> 6;
    const int l = tid & 63;
    const int r = l & 15;
    const int b = l >> 4;
    const int m0 = blockIdx.x * 32;
    const int n0 = wave * (NF * 16);

    const unsigned short* ap[2][2];
#pragma unroll
    for (int mf = 0; mf < 2; ++mf) {
        int row = min(m0 + mf * 16 + r, M - 1);  // clamped dup-read; store guarded
        ap[mf][0] = Ah + (size_t)row * K + b * 8;
        ap[mf][1] = Al + (size_t)row * K + b * 8;
    }
    const unsigned short* bp[NF][2];
#pragma unroll
    for (int nf = 0; nf < NF; ++nf) {
        int row = n0 + nf * 16 + r;
        bp[nf][0] = Bth + (size_t)row * K + b * 8;
        bp[nf][1] = Btl + (size_t)row * K + b * 8;
    }

    f4v acc[2][NF];
#pragma unroll
    for (int mf = 0; mf < 2; ++mf)
#pragma unroll
        for (int nf = 0; nf < NF; ++nf) acc[mf][nf] = (f4v){0.f, 0.f, 0.f, 0.f};

    for (int ks = 0; ks < K / 32; ++ks) {
        s8v ah[2], al[2];
#pragma unroll
        for (int mf = 0; mf < 2; ++mf) {
            ah[mf] = *reinterpret_cast<const s8v*>(ap[mf][0] + ks * 32);
            al[mf] = *reinterpret_cast<const s8v*>(ap[mf][1] + ks * 32);
        }
#pragma unroll
        for (int nf = 0; nf < NF; ++nf) {
            s8v bh = *reinterpret_cast<const s8v*>(bp[nf][0] + ks * 32);
            s8v bl = *reinterpret_cast<const s8v*>(bp[nf][1] + ks * 32);
#pragma unroll
            for (int mf = 0; mf < 2; ++mf) {
                acc[mf][nf] = __builtin_amdgcn_mfma_f32_16x16x32_bf16(ah[mf], bh, acc[mf][nf], 0, 0, 0);
                acc[mf][nf] = __builtin_amdgcn_mfma_f32_16x16x32_bf16(ah[mf], bl, acc[mf][nf], 0, 0, 0);
                acc[mf][nf] = __builtin_amdgcn_mfma_f32_16x16x32_bf16(al[mf], bh, acc[mf][nf], 0, 0, 0);
            }
        }
    }

#pragma unroll
    for (int mf = 0; mf < 2; ++mf)
#pragma unroll
        for (int i = 0; i < 4; ++i) {
            int row = m0 + mf * 16 + b * 4 + i;
            if (row < M) {
#pragma unroll
                for (int nf = 0; nf < NF; ++nf)
                    C[(size_t)row * N + n0 + nf * 16 + r] =
                        (unsigned short)bf16_rne_bits(acc[mf][nf][i]);
            }
        }
}

// ---------------- CSR SpMM over bf16 X ----------------
// Wave per row; lane holds VEC=D/64 feats (ushort4 / ushort2 loads); 8x
// unrolled gathers; fp32 accumulate. Wave id forced uniform so row bounds
// and meta[] ride the scalar path.
// SPLITOUT: relu then bf16 hi/lo writes (feeds gemm2). Else fp32 out.

template <int D, bool SPLITOUT>
__global__ __launch_bounds__(256) void spmm_bf16(const int* __restrict__ row_ptr,
                                                 const int2* __restrict__ meta,
                                                 const unsigned short* __restrict__ Xb,
                                                 float* __restrict__ Yo,
                                                 unsigned short* __restrict__ Yh,
                                                 unsigned short* __restrict__ Yl,
                                                 int nrows) {
    constexpr int VEC = D / 64;  // 4 or 2
    const int lane = threadIdx.x & 63;
    const int wid = __builtin_amdgcn_readfirstlane(threadIdx.x >> 6);
    const int r = blockIdx.x * 4 + wid;
    if (r >= nrows) return;
    const int s = row_ptr[r];
    const int e = row_ptr[r + 1];
    const unsigned short* __restrict__ base = Xb + (size_t)lane * VEC;

    float acc[VEC];
#pragma unroll
    for (int k = 0; k < VEC; ++k) acc[k] = 0.f;

    int i = s;
    for (; i + 8 <= e; i += 8) {
        int2 mm[8];
#pragma unroll
        for (int u = 0; u < 8; ++u) mm[u] = meta[i + u];
        float xv[8][VEC];
#pragma unroll
        for (int u = 0; u < 8; ++u) {
            const unsigned short* p = base + (size_t)mm[u].x * D;
            if constexpr (VEC == 4) {
                uint2 t = *reinterpret_cast<const uint2*>(p);
                unpack2(t.x, xv[u][0], xv[u][1]);
                unpack2(t.y, xv[u][2], xv[u][3]);
            } else {
                unsigned int t = *reinterpret_cast<const unsigned int*>(p);
                unpack2(t, xv[u][0], xv[u][1]);
            }
        }
#pragma unroll
        for (int u = 0; u < 8; ++u) {
            float v = __int_as_float(mm[u].y);
#pragma unroll
            for (int k = 0; k < VEC; ++k) acc[k] = fmaf(v, xv[u][k], acc[k]);
        }
    }
    for (; i < e; ++i) {
        int2 m = meta[i];
        const unsigned short* p = base + (size_t)m.x * D;
        float xv[VEC];
        if constexpr (VEC == 4) {
            uint2 t = *reinterpret_cast<const uint2*>(p);
            unpack2(t.x, xv[0], xv[1]);
            unpack2(t.y, xv[2], xv[3]);
        } else {
            unsigned int t = *reinterpret_cast<const unsigned int*>(p);
            unpack2(t, xv[0], xv[1]);
        }
        float v = __int_as_float(m.y);
#pragma unroll
        for (int k = 0; k < VEC; ++k) acc[k] = fmaf(v, xv[k], acc[k]);
    }

    if constexpr (SPLITOUT) {
        static_assert(VEC == 4, "split path assumes D=256");
        ushort4 h, l;
        float a0 = fmaxf(acc[0], 0.f), a1 = fmaxf(acc[1], 0.f);
        float a2 = fmaxf(acc[2], 0.f), a3 = fmaxf(acc[3], 0.f);
        split_hi_lo(a0, h.x, l.x);
        split_hi_lo(a1, h.y, l.y);
        split_hi_lo(a2, h.z, l.z);
        split_hi_lo(a3, h.w, l.w);
        reinterpret_cast<ushort4*>(Yh + (size_t)r * D)[lane] = h;
        reinterpret_cast<ushort4*>(Yl + (size_t)r * D)[lane] = l;
    } else {
        float* yp = Yo + (size_t)r * D + lane * VEC;
        if constexpr (VEC == 4) {
            *reinterpret_cast<float4*>(yp) = make_float4(acc[0], acc[1], acc[2], acc[3]);
        } else {
            *reinterpret_cast<float2*>(yp) = make_float2(acc[0], acc[1]);
        }
    }
}

// ---------------- launch ----------------

extern "C" void kernel_launch(void* const* d_in, const int* in_sizes, int n_in,
                              void* d_out, int out_size, void* d_ws, size_t ws_size,
                              hipStream_t stream) {
    const float* Y     = (const float*)d_in[0];
    const int*   erow  = (const int*)d_in[1];
    const int*   ecol  = (const int*)d_in[2];
    const float* eval_ = (const float*)d_in[3];
    const float* W1    = (const float*)d_in[4];
    const float* W2    = (const float*)d_in[5];
    float* out = (float*)d_out;
    const int E = in_sizes[1];
    const int N = NN;

    // Workspace (~85 MB):
    //   [0, 25.6M)     Yh   (reused as HAh after gemm1)
    //   [25.6, 51.2M)  Yl   (reused as HAl)
    //   [51.2, 76.8M)  Hb bf16 (reused as Gb after spmm1)
    //   then W splits, row_ptr/cursor/cnt/partial, meta
    char* ws = (char*)d_ws;
    unsigned short* Yh = (unsigned short*)ws;
    unsigned short* Yl = (unsigned short*)(ws + 25600000);
    unsigned short* Hb = (unsigned short*)(ws + 51200000);
    char* p = ws + 76800000;
    unsigned short* W1th = (unsigned short*)p; p += 131072;
    unsigned short* W1tl = (unsigned short*)p; p += 131072;
    unsigned short* W2th = (unsigned short*)p; p += 65536;
    unsigned short* W2tl = (unsigned short*)p; p += 65536;
    int* row_ptr = (int*)p; p += 200064;           // (N+1)*4 padded
    int* cursor  = (int*)p; p += 200000;
    int* cnt     = (int*)p; p += 200000;
    int* partial = (int*)p; p += 1024;
    int2* meta   = (int2*)p;                       // E*8 = 6.4 MB

    // CSR build (parallel scan)
    hipMemsetAsync(cnt, 0, (size_t)N * 4, stream);
    hist_kernel<<<512, 256, 0, stream>>>(erow, cnt, E);
    scan_local<<<256, 256, 0, stream>>>(cnt, row_ptr, partial, N);
    scan_tot<<<1, 256, 0, stream>>>(partial);
    scan_add<<<256, 256, 0, stream>>>(row_ptr, cursor, partial, N, E);
    scatter_kernel<<<512, 256, 0, stream>>>(erow, ecol, eval_, cursor, meta, E);

    // Input splits
    split_kernel<<<2048, 256, 0, stream>>>(Y, Yh, Yl, N * 256 / 4);
    wsplit_kernel<<<256, 256, 0, stream>>>(W1, W1th, W1tl, 256, 256);
    wsplit_kernel<<<128, 256, 0, stream>>>(W2, W2th, W2tl, 256, 128);

    // Layer 1: Hb = bf16(Y@W1); HA = relu(spmm(Hb)) -> hi/lo (alias Yh/Yl)
    gemm3p<4><<<(N + 31) / 32, 256, 0, stream>>>(Yh, Yl, W1th, W1tl, Hb, N);
    spmm_bf16<256, true><<<(N + 3) / 4, 256, 0, stream>>>(row_ptr, meta, Hb, nullptr, Yh, Yl, N);

    // Layer 2: Gb = bf16(HA@W2) (alias Hb); out = spmm(Gb)
    gemm3p<2><<<(N + 31) / 32, 256, 0, stream>>>(Yh, Yl, W2th, W2tl, Hb, N);
    spmm_bf16<128, false><<<(N + 3) / 4, 256, 0, stream>>>(row_ptr, meta, Hb, out, nullptr, nullptr, N);
}

// Round 7
// 362.091 us; speedup vs baseline: 2.3594x; 1.2103x over previous
//
#include <hip/hip_runtime.h>

// GCN 2-layer forward on MI355X (R6 resubmit):
//   split Y -> Y' = [Yh|Yl]  [M][512] bf16
//   Hb  = bf16( Y@W1 )   LDS-staged MFMA GEMM, 3-product (Ah*Bh+Al*Bh+Ah*Bl)
//   HA' = relu(spmm(A,Hb)) -> [HAh|HAl] (split in epilogue, aliases Y')
//   Gb  = bf16( HA@W2 )  same GEMM
//   out = spmm(A,Gb)
// R5 counters: gemm3p latency-bound (MfmaUtil 8.8%, HBM 7.8%, occ 31%).
// New GEMM: 128x128 tile, BK=32, global_load_lds(16B) dbuf staging, XOR
// chunk-swizzle via pre-swizzled SOURCE (write-linear, read-swizzled).

#define NN 50000

typedef short s8v __attribute__((ext_vector_type(8)));  // 8 bf16 in 4 VGPRs
typedef float f4v __attribute__((ext_vector_type(4)));
typedef unsigned int u32;

// ---------------- bf16 helpers ----------------

__device__ inline unsigned int bf16_rne_bits(float x) {
    unsigned int u = __float_as_uint(x);
    return (u + 0x7FFFu + ((u >> 16) & 1u)) >> 16;  // round-to-nearest-even
}
__device__ inline float bf16_bits_to_f32(unsigned int h) {
    return __uint_as_float(h << 16);
}
__device__ inline void split_hi_lo(float x, unsigned short& hi, unsigned short& lo) {
    unsigned int h = bf16_rne_bits(x);
    hi = (unsigned short)h;
    lo = (unsigned short)bf16_rne_bits(x - bf16_bits_to_f32(h));
}
__device__ inline void unpack2(unsigned int u, float& f0, float& f1) {
    f0 = __uint_as_float(u << 16);
    f1 = __uint_as_float(u & 0xFFFF0000u);
}

__device__ inline void gl_lds16(const void* g, void* l) {
    __builtin_amdgcn_global_load_lds(
        (const __attribute__((address_space(1))) u32*)g,
        (__attribute__((address_space(3))) u32*)l, 16, 0, 0);
}

// ---------------- CSR build ----------------

__global__ void hist_kernel(const int* __restrict__ erow, int* __restrict__ cnt, int E) {
    int i = blockIdx.x * blockDim.x + threadIdx.x;
    int stride = gridDim.x * blockDim.x;
    for (; i < E; i += stride) atomicAdd(&cnt[erow[i]], 1);
}

#define SCAN_CHUNK 196

__global__ __launch_bounds__(256) void scan_local(const int* __restrict__ cnt,
                                                  int* __restrict__ row_ptr,
                                                  int* __restrict__ partial, int n) {
    __shared__ int lds[256];
    int t = threadIdx.x, b = blockIdx.x;
    int idx = b * SCAN_CHUNK + t;
    int v = (t < SCAN_CHUNK && idx < n) ? cnt[idx] : 0;
    lds[t] = v;
    __syncthreads();
#pragma unroll
    for (int off = 1; off < 256; off <<= 1) {
        int a = (t >= off) ? lds[t - off] : 0;
        __syncthreads();
        lds[t] += a;
        __syncthreads();
    }
    if (t < SCAN_CHUNK && idx < n) row_ptr[idx] = lds[t] - v;
    if (t == 255) partial[b] = lds[255];
}

__global__ __launch_bounds__(256) void scan_tot(int* __restrict__ partial) {
    __shared__ int lds[256];
    int t = threadIdx.x;
    int v = partial[t];
    lds[t] = v;
    __syncthreads();
#pragma unroll
    for (int off = 1; off < 256; off <<= 1) {
        int a = (t >= off) ? lds[t - off] : 0;
        __syncthreads();
        lds[t] += a;
        __syncthreads();
    }
    partial[t] = lds[t] - v;
}

__global__ __launch_bounds__(256) void scan_add(int* __restrict__ row_ptr,
                                                int* __restrict__ cursor,
                                                const int* __restrict__ partial,
                                                int n, int E) {
    int t = threadIdx.x, b = blockIdx.x;
    int idx = b * SCAN_CHUNK + t;
    if (t < SCAN_CHUNK && idx < n) {
        int rp = row_ptr[idx] + partial[b];
        row_ptr[idx] = rp;
        cursor[idx] = rp;
    }
    if (b == 0 && t == 0) row_ptr[n] = E;
}

__global__ void scatter_kernel(const int* __restrict__ erow, const int* __restrict__ ecol,
                               const float* __restrict__ eval_, int* __restrict__ cursor,
                               int2* __restrict__ meta, int E) {
    int i = blockIdx.x * blockDim.x + threadIdx.x;
    int stride = gridDim.x * blockDim.x;
    for (; i < E; i += stride) {
        int r = erow[i];
        int pos = atomicAdd(&cursor[r], 1);
        meta[pos] = make_int2(ecol[i], __float_as_int(eval_[i]));
    }
}

// ---------------- split passes ----------------

// Y [M][256] f32 -> Y' [M][512] bf16 = [Yh(256) | Yl(256)]
__global__ __launch_bounds__(256) void split_kernel(const float* __restrict__ X,
                                                    unsigned short* __restrict__ Xp, int n4) {
    int i = blockIdx.x * blockDim.x + threadIdx.x;
    int stride = gridDim.x * blockDim.x;
    for (; i < n4; i += stride) {
        float4 v = reinterpret_cast<const float4*>(X)[i];
        ushort4 h, l;
        split_hi_lo(v.x, h.x, l.x);
        split_hi_lo(v.y, h.y, l.y);
        split_hi_lo(v.z, h.z, l.z);
        split_hi_lo(v.w, h.w, l.w);
        int row = i >> 6, c4 = (i & 63) * 4;
        *reinterpret_cast<ushort4*>(Xp + (size_t)row * 512 + c4) = h;
        *reinterpret_cast<ushort4*>(Xp + (size_t)row * 512 + 256 + c4) = l;
    }
}

// W [K=256][N] f32 -> Bth, Btl  [N][256] bf16 (transposed hi / lo)
__global__ __launch_bounds__(256) void wsplit_kernel(const float* __restrict__ W,
                                                     unsigned short* __restrict__ Bth,
                                                     unsigned short* __restrict__ Btl,
                                                     int K, int N) {
    int idx = blockIdx.x * blockDim.x + threadIdx.x;
    if (idx >= K * N) return;
    int k = idx / N, n = idx - k * N;
    unsigned short h, l;
    split_hi_lo(W[idx], h, l);
    Bth[(size_t)n * K + k] = h;
    Btl[(size_t)n * K + k] = l;
}

// ---------------- LDS-staged 3-product MFMA GEMM ----------------
// C[M][N] bf16 = A[M][256]*B[256][N] with A' = [Ah|Al] [M][512],
// B as Bth/Btl [N][256]. Tile 128x128, BK=32. 256 thr = 4 waves; wave w owns
// quadrant rows (w&1)*64, cols (w>>1)*64, 4x4 frags of 16x16x32.
// K-schedule (16 steps over A'): steps 0..7 (Ah): MFMA vs Bh AND Bl chunks;
// steps 8..15 (Al): vs Bh only.  => Ah*Bh + Ah*Bl + Al*Bh.
// LDS per buf: A 8KB | Bh 8KB | Bl 8KB = 24KB; dbuf = 48KB.
// 16B-chunk XOR swizzle cp = cl ^ ((row>>1)&3): applied on the staging SOURCE
// address (global_load_lds dest must stay linear) and on the ds_read address.
__global__ __launch_bounds__(256) void gemm_tile(const unsigned short* __restrict__ Ap,
                                                 const unsigned short* __restrict__ Bth,
                                                 const unsigned short* __restrict__ Btl,
                                                 unsigned short* __restrict__ C,
                                                 int M, int N) {
    __shared__ unsigned short lds[2][12288];
    const int tid = threadIdx.x;
    const int wave = tid >> 6, lane = tid & 63;
    const int r = lane & 15, b = lane >> 4;
    const int m0 = blockIdx.x * 128, n0 = blockIdx.y * 128;
    const int wrow = (wave & 1) * 64, wcol = (wave >> 1) * 64;

    f4v acc[4][4];
#pragma unroll
    for (int mf = 0; mf < 4; ++mf)
#pragma unroll
        for (int nf = 0; nf < 4; ++nf) acc[mf][nf] = (f4v){0.f, 0.f, 0.f, 0.f};

    // staging: 2 rounds of 4KB (4 waves x 1KB) per 8KB tile-chunk
    auto stage = [&](int buf, int s) {
        char* lb = (char*)&lds[buf][0];
#pragma unroll
        for (int c = 0; c < 2; ++c) {
            int uni = c * 4096 + wave * 1024;        // wave-uniform dest offset
            int oc = uni + lane * 16;                // this lane's dest byte
            int row = oc >> 6;                       // tile row (64B per row)
            int cl = ((oc >> 4) & 3) ^ ((row >> 1) & 3);  // logical 16B chunk
            int arow = min(m0 + row, M - 1);
            gl_lds16(Ap + (size_t)arow * 512 + s * 32 + cl * 8, lb + uni);
            int bk = (s & 7) * 32 + cl * 8;
            const size_t boff = (size_t)(n0 + row) * 256 + bk;
            gl_lds16(Bth + boff, lb + 8192 + uni);
            if (s < 8) gl_lds16(Btl + boff, lb + 16384 + uni);
        }
    };

    stage(0, 0);
    __syncthreads();

    int buf = 0;
    for (int s = 0; s < 16; ++s) {
        if (s < 15) stage(buf ^ 1, s + 1);

        const char* lb = (const char*)&lds[buf][0];
        s8v af[4], bh[4], bl[4];
#pragma unroll
        for (int mf = 0; mf < 4; ++mf) {
            int trow = wrow + mf * 16 + r;
            int cp = b ^ ((trow >> 1) & 3);
            af[mf] = *reinterpret_cast<const s8v*>(lb + trow * 64 + cp * 16);
        }
#pragma unroll
        for (int nf = 0; nf < 4; ++nf) {
            int trow = wcol + nf * 16 + r;
            int cp = b ^ ((trow >> 1) & 3);
            bh[nf] = *reinterpret_cast<const s8v*>(lb + 8192 + trow * 64 + cp * 16);
            if (s < 8)
                bl[nf] = *reinterpret_cast<const s8v*>(lb + 16384 + trow * 64 + cp * 16);
        }
#pragma unroll
        for (int mf = 0; mf < 4; ++mf)
#pragma unroll
            for (int nf = 0; nf < 4; ++nf)
                acc[mf][nf] = __builtin_amdgcn_mfma_f32_16x16x32_bf16(af[mf], bh[nf], acc[mf][nf], 0, 0, 0);
        if (s < 8) {
#pragma unroll
            for (int mf = 0; mf < 4; ++mf)
#pragma unroll
                for (int nf = 0; nf < 4; ++nf)
                    acc[mf][nf] = __builtin_amdgcn_mfma_f32_16x16x32_bf16(af[mf], bl[nf], acc[mf][nf], 0, 0, 0);
        }
        __syncthreads();
        buf ^= 1;
    }

    // epilogue: D frag col = lane&15, row = 4*(lane>>4)+i  (m89/m91-verified)
#pragma unroll
    for (int mf = 0; mf < 4; ++mf)
#pragma unroll
        for (int i = 0; i < 4; ++i) {
            int grow = m0 + wrow + mf * 16 + b * 4 + i;
            if (grow < M) {
#pragma unroll
                for (int nf = 0; nf < 4; ++nf)
                    C[(size_t)grow * N + n0 + wcol + nf * 16 + r] =
                        (unsigned short)bf16_rne_bits(acc[mf][nf][i]);
            }
        }
}

// ---------------- CSR SpMM over bf16 X ----------------
// Wave per row; lane holds VEC=D/64 feats; 8x unrolled gathers; fp32 accum.
// SPLITOUT: relu -> [HAh|HAl] row-stride 512 into Ysplit. Else fp32 out.

template <int D, bool SPLITOUT>
__global__ __launch_bounds__(256) void spmm_bf16(const int* __restrict__ row_ptr,
                                                 const int2* __restrict__ meta,
                                                 const unsigned short* __restrict__ Xb,
                                                 float* __restrict__ Yo,
                                                 unsigned short* __restrict__ Ysplit,
                                                 int nrows) {
    constexpr int VEC = D / 64;  // 4 or 2
    const int lane = threadIdx.x & 63;
    const int wid = __builtin_amdgcn_readfirstlane(threadIdx.x >> 6);
    const int r = blockIdx.x * 4 + wid;
    if (r >= nrows) return;
    const int s = row_ptr[r];
    const int e = row_ptr[r + 1];
    const unsigned short* __restrict__ base = Xb + (size_t)lane * VEC;

    float acc[VEC];
#pragma unroll
    for (int k = 0; k < VEC; ++k) acc[k] = 0.f;

    int i = s;
    for (; i + 8 <= e; i += 8) {
        int2 mm[8];
#pragma unroll
        for (int u = 0; u < 8; ++u) mm[u] = meta[i + u];
        float xv[8][VEC];
#pragma unroll
        for (int u = 0; u < 8; ++u) {
            const unsigned short* p = base + (size_t)mm[u].x * D;
            if constexpr (VEC == 4) {
                uint2 t = *reinterpret_cast<const uint2*>(p);
                unpack2(t.x, xv[u][0], xv[u][1]);
                unpack2(t.y, xv[u][2], xv[u][3]);
            } else {
                unsigned int t = *reinterpret_cast<const unsigned int*>(p);
                unpack2(t, xv[u][0], xv[u][1]);
            }
        }
#pragma unroll
        for (int u = 0; u < 8; ++u) {
            float v = __int_as_float(mm[u].y);
#pragma unroll
            for (int k = 0; k < VEC; ++k) acc[k] = fmaf(v, xv[u][k], acc[k]);
        }
    }
    for (; i < e; ++i) {
        int2 m = meta[i];
        const unsigned short* p = base + (size_t)m.x * D;
        float xv[VEC];
        if constexpr (VEC == 4) {
            uint2 t = *reinterpret_cast<const uint2*>(p);
            unpack2(t.x, xv[0], xv[1]);
            unpack2(t.y, xv[2], xv[3]);
        } else {
            unsigned int t = *reinterpret_cast<const unsigned int*>(p);
            unpack2(t, xv[0], xv[1]);
        }
        float v = __int_as_float(m.y);
#pragma unroll
        for (int k = 0; k < VEC; ++k) acc[k] = fmaf(v, xv[k], acc[k]);
    }

    if constexpr (SPLITOUT) {
        static_assert(VEC == 4, "split path assumes D=256");
        ushort4 h, l;
        float a0 = fmaxf(acc[0], 0.f), a1 = fmaxf(acc[1], 0.f);
        float a2 = fmaxf(acc[2], 0.f), a3 = fmaxf(acc[3], 0.f);
        split_hi_lo(a0, h.x, l.x);
        split_hi_lo(a1, h.y, l.y);
        split_hi_lo(a2, h.z, l.z);
        split_hi_lo(a3, h.w, l.w);
        reinterpret_cast<ushort4*>(Ysplit + (size_t)r * 512)[lane] = h;
        reinterpret_cast<ushort4*>(Ysplit + (size_t)r * 512 + 256)[lane] = l;
    } else {
        float* yp = Yo + (size_t)r * D + lane * VEC;
        if constexpr (VEC == 4) {
            *reinterpret_cast<float4*>(yp) = make_float4(acc[0], acc[1], acc[2], acc[3]);
        } else {
            *reinterpret_cast<float2*>(yp) = make_float2(acc[0], acc[1]);
        }
    }
}

// ---------------- launch ----------------

extern "C" void kernel_launch(void* const* d_in, const int* in_sizes, int n_in,
                              void* d_out, int out_size, void* d_ws, size_t ws_size,
                              hipStream_t stream) {
    const float* Y     = (const float*)d_in[0];
    const int*   erow  = (const int*)d_in[1];
    const int*   ecol  = (const int*)d_in[2];
    const float* eval_ = (const float*)d_in[3];
    const float* W1    = (const float*)d_in[4];
    const float* W2    = (const float*)d_in[5];
    float* out = (float*)d_out;
    const int E = in_sizes[1];
    const int N = NN;

    // Workspace (~84 MB):
    //   [0, 51.2M)     Y' = [Yh|Yl]  (aliased as HA' = [HAh|HAl] after gemm1)
    //   [51.2, 76.8M)  Hb bf16 M*256 (reused as Gb M*128)
    //   then W splits, row_ptr/cursor/cnt/partial, meta
    char* ws = (char*)d_ws;
    unsigned short* Yp = (unsigned short*)ws;
    unsigned short* Hb = (unsigned short*)(ws + 51200000);
    char* p = ws + 76800000;
    unsigned short* B1th = (unsigned short*)p; p += 131072;
    unsigned short* B1tl = (unsigned short*)p; p += 131072;
    unsigned short* B2th = (unsigned short*)p; p += 65536;
    unsigned short* B2tl = (unsigned short*)p; p += 65536;
    int* row_ptr = (int*)p; p += 200064;
    int* cursor  = (int*)p; p += 200000;
    int* cnt     = (int*)p; p += 200000;
    int* partial = (int*)p; p += 1024;
    int2* meta   = (int2*)p;  // E*8 = 6.4 MB

    // CSR build
    hipMemsetAsync(cnt, 0, (size_t)N * 4, stream);
    hist_kernel<<<512, 256, 0, stream>>>(erow, cnt, E);
    scan_local<<<256, 256, 0, stream>>>(cnt, row_ptr, partial, N);
    scan_tot<<<1, 256, 0, stream>>>(partial);
    scan_add<<<256, 256, 0, stream>>>(row_ptr, cursor, partial, N, E);
    scatter_kernel<<<512, 256, 0, stream>>>(erow, ecol, eval_, cursor, meta, E);

    // Input splits
    split_kernel<<<2048, 256, 0, stream>>>(Y, Yp, N * 64);
    wsplit_kernel<<<256, 256, 0, stream>>>(W1, B1th, B1tl, 256, 256);
    wsplit_kernel<<<128, 256, 0, stream>>>(W2, B2th, B2tl, 256, 128);

    // Layer 1
    gemm_tile<<<dim3(391, 2), 256, 0, stream>>>(Yp, B1th, B1tl, Hb, N, 256);
    spmm_bf16<256, true><<<(N + 3) / 4, 256, 0, stream>>>(row_ptr, meta, Hb, nullptr, Yp, N);

    // Layer 2 (HA' aliases Yp; Gb aliases Hb)
    gemm_tile<<<dim3(391, 1), 256, 0, stream>>>(Yp, B2th, B2tl, Hb, N, 128);
    spmm_bf16<128, false><<<(N + 3) / 4, 256, 0, stream>>>(row_ptr, meta, Hb, out, nullptr, N);
}

// Round 8
// 358.619 us; speedup vs baseline: 2.3822x; 1.0097x over previous
//
#include <hip/hip_runtime.h>

// GCN 2-layer forward on MI355X (R8):
//   split Y -> Y' = [Yh|Yl]  [M][512] bf16
//   Hb  = bf16( Y@W1 )   LDS-staged MFMA GEMM, 3-product (Ah*Bh+Al*Bh+Ah*Bl)
//   HA' = relu(spmm(A,Hb)) -> [HAh|HAl] (split in epilogue, aliases Y')
//   Gb  = bf16( HA@W2 )  same GEMM
//   out = spmm(A,Gb)
// R7: scatter_kernel is #1 (67us, VALUBusy 0.3%, 0.87 TB/s, 8x write-amp).
// Fix: 4-edge batches per thread (vector loads, 4 independent returning
// atomics in flight, then 4 stores) + grid 782. Same for hist_kernel.

#define NN 50000

typedef short s8v __attribute__((ext_vector_type(8)));  // 8 bf16 in 4 VGPRs
typedef float f4v __attribute__((ext_vector_type(4)));
typedef unsigned int u32;

// ---------------- bf16 helpers ----------------

__device__ inline unsigned int bf16_rne_bits(float x) {
    unsigned int u = __float_as_uint(x);
    return (u + 0x7FFFu + ((u >> 16) & 1u)) >> 16;  // round-to-nearest-even
}
__device__ inline float bf16_bits_to_f32(unsigned int h) {
    return __uint_as_float(h << 16);
}
__device__ inline void split_hi_lo(float x, unsigned short& hi, unsigned short& lo) {
    unsigned int h = bf16_rne_bits(x);
    hi = (unsigned short)h;
    lo = (unsigned short)bf16_rne_bits(x - bf16_bits_to_f32(h));
}
__device__ inline void unpack2(unsigned int u, float& f0, float& f1) {
    f0 = __uint_as_float(u << 16);
    f1 = __uint_as_float(u & 0xFFFF0000u);
}

__device__ inline void gl_lds16(const void* g, void* l) {
    __builtin_amdgcn_global_load_lds(
        (const __attribute__((address_space(1))) u32*)g,
        (__attribute__((address_space(3))) u32*)l, 16, 0, 0);
}

// ---------------- CSR build ----------------

// 4 edges per thread; non-returning atomics pipeline freely.
__global__ void hist_kernel(const int* __restrict__ erow, int* __restrict__ cnt, int E) {
    int i0 = (blockIdx.x * blockDim.x + threadIdx.x) * 4;
    if (i0 + 4 <= E) {
        int4 r = *reinterpret_cast<const int4*>(&erow[i0]);
        atomicAdd(&cnt[r.x], 1);
        atomicAdd(&cnt[r.y], 1);
        atomicAdd(&cnt[r.z], 1);
        atomicAdd(&cnt[r.w], 1);
    } else {
        for (int i = i0; i < E; ++i) atomicAdd(&cnt[erow[i]], 1);
    }
}

#define SCAN_CHUNK 196

__global__ __launch_bounds__(256) void scan_local(const int* __restrict__ cnt,
                                                  int* __restrict__ row_ptr,
                                                  int* __restrict__ partial, int n) {
    __shared__ int lds[256];
    int t = threadIdx.x, b = blockIdx.x;
    int idx = b * SCAN_CHUNK + t;
    int v = (t < SCAN_CHUNK && idx < n) ? cnt[idx] : 0;
    lds[t] = v;
    __syncthreads();
#pragma unroll
    for (int off = 1; off < 256; off <<= 1) {
        int a = (t >= off) ? lds[t - off] : 0;
        __syncthreads();
        lds[t] += a;
        __syncthreads();
    }
    if (t < SCAN_CHUNK && idx < n) row_ptr[idx] = lds[t] - v;
    if (t == 255) partial[b] = lds[255];
}

__global__ __launch_bounds__(256) void scan_tot(int* __restrict__ partial) {
    __shared__ int lds[256];
    int t = threadIdx.x;
    int v = partial[t];
    lds[t] = v;
    __syncthreads();
#pragma unroll
    for (int off = 1; off < 256; off <<= 1) {
        int a = (t >= off) ? lds[t - off] : 0;
        __syncthreads();
        lds[t] += a;
        __syncthreads();
    }
    partial[t] = lds[t] - v;
}

__global__ __launch_bounds__(256) void scan_add(int* __restrict__ row_ptr,
                                                int* __restrict__ cursor,
                                                const int* __restrict__ partial,
                                                int n, int E) {
    int t = threadIdx.x, b = blockIdx.x;
    int idx = b * SCAN_CHUNK + t;
    if (t < SCAN_CHUNK && idx < n) {
        int rp = row_ptr[idx] + partial[b];
        row_ptr[idx] = rp;
        cursor[idx] = rp;
    }
    if (b == 0 && t == 0) row_ptr[n] = E;
}

// 4 edges per thread: vector loads, 4 independent returning atomics in
// flight, then 4 independent scattered stores (R7: 1-deep chain was 67us).
__global__ void scatter_kernel(const int* __restrict__ erow, const int* __restrict__ ecol,
                               const float* __restrict__ eval_, int* __restrict__ cursor,
                               int2* __restrict__ meta, int E) {
    int i0 = (blockIdx.x * blockDim.x + threadIdx.x) * 4;
    if (i0 + 4 <= E) {
        int4 r = *reinterpret_cast<const int4*>(&erow[i0]);
        int4 c = *reinterpret_cast<const int4*>(&ecol[i0]);
        float4 v = *reinterpret_cast<const float4*>(&eval_[i0]);
        int p0 = atomicAdd(&cursor[r.x], 1);
        int p1 = atomicAdd(&cursor[r.y], 1);
        int p2 = atomicAdd(&cursor[r.z], 1);
        int p3 = atomicAdd(&cursor[r.w], 1);
        meta[p0] = make_int2(c.x, __float_as_int(v.x));
        meta[p1] = make_int2(c.y, __float_as_int(v.y));
        meta[p2] = make_int2(c.z, __float_as_int(v.z));
        meta[p3] = make_int2(c.w, __float_as_int(v.w));
    } else {
        for (int i = i0; i < E; ++i) {
            int pos = atomicAdd(&cursor[erow[i]], 1);
            meta[pos] = make_int2(ecol[i], __float_as_int(eval_[i]));
        }
    }
}

// ---------------- split passes ----------------

// Y [M][256] f32 -> Y' [M][512] bf16 = [Yh(256) | Yl(256)]
__global__ __launch_bounds__(256) void split_kernel(const float* __restrict__ X,
                                                    unsigned short* __restrict__ Xp, int n4) {
    int i = blockIdx.x * blockDim.x + threadIdx.x;
    int stride = gridDim.x * blockDim.x;
    for (; i < n4; i += stride) {
        float4 v = reinterpret_cast<const float4*>(X)[i];
        ushort4 h, l;
        split_hi_lo(v.x, h.x, l.x);
        split_hi_lo(v.y, h.y, l.y);
        split_hi_lo(v.z, h.z, l.z);
        split_hi_lo(v.w, h.w, l.w);
        int row = i >> 6, c4 = (i & 63) * 4;
        *reinterpret_cast<ushort4*>(Xp + (size_t)row * 512 + c4) = h;
        *reinterpret_cast<ushort4*>(Xp + (size_t)row * 512 + 256 + c4) = l;
    }
}

// W [K=256][N] f32 -> Bth, Btl  [N][256] bf16 (transposed hi / lo)
__global__ __launch_bounds__(256) void wsplit_kernel(const float* __restrict__ W,
                                                     unsigned short* __restrict__ Bth,
                                                     unsigned short* __restrict__ Btl,
                                                     int K, int N) {
    int idx = blockIdx.x * blockDim.x + threadIdx.x;
    if (idx >= K * N) return;
    int k = idx / N, n = idx - k * N;
    unsigned short h, l;
    split_hi_lo(W[idx], h, l);
    Bth[(size_t)n * K + k] = h;
    Btl[(size_t)n * K + k] = l;
}

// ---------------- LDS-staged 3-product MFMA GEMM ----------------
// C[M][N] bf16 = A[M][256]*B[256][N] with A' = [Ah|Al] [M][512],
// B as Bth/Btl [N][256]. Tile 128x128, BK=32. 256 thr = 4 waves; wave w owns
// quadrant rows (w&1)*64, cols (w>>1)*64, 4x4 frags of 16x16x32.
// K-schedule (16 steps over A'): steps 0..7 (Ah): MFMA vs Bh AND Bl chunks;
// steps 8..15 (Al): vs Bh only.  => Ah*Bh + Ah*Bl + Al*Bh.
// 16B-chunk XOR swizzle applied on staging SOURCE + ds_read (rule 21).
__global__ __launch_bounds__(256) void gemm_tile(const unsigned short* __restrict__ Ap,
                                                 const unsigned short* __restrict__ Bth,
                                                 const unsigned short* __restrict__ Btl,
                                                 unsigned short* __restrict__ C,
                                                 int M, int N) {
    __shared__ unsigned short lds[2][12288];
    const int tid = threadIdx.x;
    const int wave = tid >> 6, lane = tid & 63;
    const int r = lane & 15, b = lane >> 4;
    const int m0 = blockIdx.x * 128, n0 = blockIdx.y * 128;
    const int wrow = (wave & 1) * 64, wcol = (wave >> 1) * 64;

    f4v acc[4][4];
#pragma unroll
    for (int mf = 0; mf < 4; ++mf)
#pragma unroll
        for (int nf = 0; nf < 4; ++nf) acc[mf][nf] = (f4v){0.f, 0.f, 0.f, 0.f};

    auto stage = [&](int buf, int s) {
        char* lb = (char*)&lds[buf][0];
#pragma unroll
        for (int c = 0; c < 2; ++c) {
            int uni = c * 4096 + wave * 1024;        // wave-uniform dest offset
            int oc = uni + lane * 16;                // this lane's dest byte
            int row = oc >> 6;                       // tile row (64B per row)
            int cl = ((oc >> 4) & 3) ^ ((row >> 1) & 3);  // logical 16B chunk
            int arow = min(m0 + row, M - 1);
            gl_lds16(Ap + (size_t)arow * 512 + s * 32 + cl * 8, lb + uni);
            int bk = (s & 7) * 32 + cl * 8;
            const size_t boff = (size_t)(n0 + row) * 256 + bk;
            gl_lds16(Bth + boff, lb + 8192 + uni);
            if (s < 8) gl_lds16(Btl + boff, lb + 16384 + uni);
        }
    };

    stage(0, 0);
    __syncthreads();

    int buf = 0;
    for (int s = 0; s < 16; ++s) {
        if (s < 15) stage(buf ^ 1, s + 1);

        const char* lb = (const char*)&lds[buf][0];
        s8v af[4], bh[4], bl[4];
#pragma unroll
        for (int mf = 0; mf < 4; ++mf) {
            int trow = wrow + mf * 16 + r;
            int cp = b ^ ((trow >> 1) & 3);
            af[mf] = *reinterpret_cast<const s8v*>(lb + trow * 64 + cp * 16);
        }
#pragma unroll
        for (int nf = 0; nf < 4; ++nf) {
            int trow = wcol + nf * 16 + r;
            int cp = b ^ ((trow >> 1) & 3);
            bh[nf] = *reinterpret_cast<const s8v*>(lb + 8192 + trow * 64 + cp * 16);
            if (s < 8)
                bl[nf] = *reinterpret_cast<const s8v*>(lb + 16384 + trow * 64 + cp * 16);
        }
#pragma unroll
        for (int mf = 0; mf < 4; ++mf)
#pragma unroll
            for (int nf = 0; nf < 4; ++nf)
                acc[mf][nf] = __builtin_amdgcn_mfma_f32_16x16x32_bf16(af[mf], bh[nf], acc[mf][nf], 0, 0, 0);
        if (s < 8) {
#pragma unroll
            for (int mf = 0; mf < 4; ++mf)
#pragma unroll
                for (int nf = 0; nf < 4; ++nf)
                    acc[mf][nf] = __builtin_amdgcn_mfma_f32_16x16x32_bf16(af[mf], bl[nf], acc[mf][nf], 0, 0, 0);
        }
        __syncthreads();
        buf ^= 1;
    }

    // epilogue: D frag col = lane&15, row = 4*(lane>>4)+i  (m89/m91-verified)
#pragma unroll
    for (int mf = 0; mf < 4; ++mf)
#pragma unroll
        for (int i = 0; i < 4; ++i) {
            int grow = m0 + wrow + mf * 16 + b * 4 + i;
            if (grow < M) {
#pragma unroll
                for (int nf = 0; nf < 4; ++nf)
                    C[(size_t)grow * N + n0 + wcol + nf * 16 + r] =
                        (unsigned short)bf16_rne_bits(acc[mf][nf][i]);
            }
        }
}

// ---------------- CSR SpMM over bf16 X ----------------
// Wave per row; lane holds VEC=D/64 feats; 8x unrolled gathers; fp32 accum.
// SPLITOUT: relu -> [HAh|HAl] row-stride 512 into Ysplit. Else fp32 out.

template <int D, bool SPLITOUT>
__global__ __launch_bounds__(256) void spmm_bf16(const int* __restrict__ row_ptr,
                                                 const int2* __restrict__ meta,
                                                 const unsigned short* __restrict__ Xb,
                                                 float* __restrict__ Yo,
                                                 unsigned short* __restrict__ Ysplit,
                                                 int nrows) {
    constexpr int VEC = D / 64;  // 4 or 2
    const int lane = threadIdx.x & 63;
    const int wid = __builtin_amdgcn_readfirstlane(threadIdx.x >> 6);
    const int r = blockIdx.x * 4 + wid;
    if (r >= nrows) return;
    const int s = row_ptr[r];
    const int e = row_ptr[r + 1];
    const unsigned short* __restrict__ base = Xb + (size_t)lane * VEC;

    float acc[VEC];
#pragma unroll
    for (int k = 0; k < VEC; ++k) acc[k] = 0.f;

    int i = s;
    for (; i + 8 <= e; i += 8) {
        int2 mm[8];
#pragma unroll
        for (int u = 0; u < 8; ++u) mm[u] = meta[i + u];
        float xv[8][VEC];
#pragma unroll
        for (int u = 0; u < 8; ++u) {
            const unsigned short* p = base + (size_t)mm[u].x * D;
            if constexpr (VEC == 4) {
                uint2 t = *reinterpret_cast<const uint2*>(p);
                unpack2(t.x, xv[u][0], xv[u][1]);
                unpack2(t.y, xv[u][2], xv[u][3]);
            } else {
                unsigned int t = *reinterpret_cast<const unsigned int*>(p);
                unpack2(t, xv[u][0], xv[u][1]);
            }
        }
#pragma unroll
        for (int u = 0; u < 8; ++u) {
            float v = __int_as_float(mm[u].y);
#pragma unroll
            for (int k = 0; k < VEC; ++k) acc[k] = fmaf(v, xv[u][k], acc[k]);
        }
    }
    for (; i < e; ++i) {
        int2 m = meta[i];
        const unsigned short* p = base + (size_t)m.x * D;
        float xv[VEC];
        if constexpr (VEC == 4) {
            uint2 t = *reinterpret_cast<const uint2*>(p);
            unpack2(t.x, xv[0], xv[1]);
            unpack2(t.y, xv[2], xv[3]);
        } else {
            unsigned int t = *reinterpret_cast<const unsigned int*>(p);
            unpack2(t, xv[0], xv[1]);
        }
        float v = __int_as_float(m.y);
#pragma unroll
        for (int k = 0; k < VEC; ++k) acc[k] = fmaf(v, xv[k], acc[k]);
    }

    if constexpr (SPLITOUT) {
        static_assert(VEC == 4, "split path assumes D=256");
        ushort4 h, l;
        float a0 = fmaxf(acc[0], 0.f), a1 = fmaxf(acc[1], 0.f);
        float a2 = fmaxf(acc[2], 0.f), a3 = fmaxf(acc[3], 0.f);
        split_hi_lo(a0, h.x, l.x);
        split_hi_lo(a1, h.y, l.y);
        split_hi_lo(a2, h.z, l.z);
        split_hi_lo(a3, h.w, l.w);
        reinterpret_cast<ushort4*>(Ysplit + (size_t)r * 512)[lane] = h;
        reinterpret_cast<ushort4*>(Ysplit + (size_t)r * 512 + 256)[lane] = l;
    } else {
        float* yp = Yo + (size_t)r * D + lane * VEC;
        if constexpr (VEC == 4) {
            *reinterpret_cast<float4*>(yp) = make_float4(acc[0], acc[1], acc[2], acc[3]);
        } else {
            *reinterpret_cast<float2*>(yp) = make_float2(acc[0], acc[1]);
        }
    }
}

// ---------------- launch ----------------

extern "C" void kernel_launch(void* const* d_in, const int* in_sizes, int n_in,
                              void* d_out, int out_size, void* d_ws, size_t ws_size,
                              hipStream_t stream) {
    const float* Y     = (const float*)d_in[0];
    const int*   erow  = (const int*)d_in[1];
    const int*   ecol  = (const int*)d_in[2];
    const float* eval_ = (const float*)d_in[3];
    const float* W1    = (const float*)d_in[4];
    const float* W2    = (const float*)d_in[5];
    float* out = (float*)d_out;
    const int E = in_sizes[1];
    const int N = NN;

    // Workspace (~84 MB):
    //   [0, 51.2M)     Y' = [Yh|Yl]  (aliased as HA' = [HAh|HAl] after gemm1)
    //   [51.2, 76.8M)  Hb bf16 M*256 (reused as Gb M*128)
    //   then W splits, row_ptr/cursor/cnt/partial, meta
    char* ws = (char*)d_ws;
    unsigned short* Yp = (unsigned short*)ws;
    unsigned short* Hb = (unsigned short*)(ws + 51200000);
    char* p = ws + 76800000;
    unsigned short* B1th = (unsigned short*)p; p += 131072;
    unsigned short* B1tl = (unsigned short*)p; p += 131072;
    unsigned short* B2th = (unsigned short*)p; p += 65536;
    unsigned short* B2tl = (unsigned short*)p; p += 65536;
    int* row_ptr = (int*)p; p += 200064;
    int* cursor  = (int*)p; p += 200000;
    int* cnt     = (int*)p; p += 200000;
    int* partial = (int*)p; p += 1024;
    int2* meta   = (int2*)p;  // E*8 = 6.4 MB

    const int eb = (E + 1023) / 1024;  // 4 edges/thread

    // CSR build
    hipMemsetAsync(cnt, 0, (size_t)N * 4, stream);
    hist_kernel<<<eb, 256, 0, stream>>>(erow, cnt, E);
    scan_local<<<256, 256, 0, stream>>>(cnt, row_ptr, partial, N);
    scan_tot<<<1, 256, 0, stream>>>(partial);
    scan_add<<<256, 256, 0, stream>>>(row_ptr, cursor, partial, N, E);
    scatter_kernel<<<eb, 256, 0, stream>>>(erow, ecol, eval_, cursor, meta, E);

    // Input splits
    split_kernel<<<2048, 256, 0, stream>>>(Y, Yp, N * 64);
    wsplit_kernel<<<256, 256, 0, stream>>>(W1, B1th, B1tl, 256, 256);
    wsplit_kernel<<<128, 256, 0, stream>>>(W2, B2th, B2tl, 256, 128);

    // Layer 1
    gemm_tile<<<dim3(391, 2), 256, 0, stream>>>(Yp, B1th, B1tl, Hb, N, 256);
    spmm_bf16<256, true><<<(N + 3) / 4, 256, 0, stream>>>(row_ptr, meta, Hb, nullptr, Yp, N);

    // Layer 2 (HA' aliases Yp; Gb aliases Hb)
    gemm_tile<<<dim3(391, 1), 256, 0, stream>>>(Yp, B2th, B2tl, Hb, N, 128);
    spmm_bf16<128, false><<<(N + 3) / 4, 256, 0, stream>>>(row_ptr, meta, Hb, out, nullptr, N);
}